// Round 1
// baseline (1726.156 us; speedup 1.0000x reference)
//
#include <hip/hip_runtime.h>
#include <math.h>

#define NMS_TH 0.3f

#define N_OBJ 512
#define N_CLS 151
#define REL_DIM 4096
#define N_REL 65536
#define N_RELCLS 51

#define BM 128
#define BN 64
#define BK 64
#define SA 72  /* LDS leading-dim in shorts: BK + 8 pad -> frag b128 reads are 2-way (free) */

#define OUT_PRED_OFF (N_OBJ * N_CLS)          /* 77312 */
#define OUT_REL_OFF  (OUT_PRED_OFF + N_OBJ)   /* 77824 */

#define NMS_BLOCKS 150
#define COPY_BLOCKS 8
#define GEMM_BLOCK0 (NMS_BLOCKS + COPY_BLOCKS)
#define GEMM_BLOCKS (N_REL / BM)              /* 512 */

typedef __attribute__((ext_vector_type(8))) short bf16x8;
typedef __attribute__((ext_vector_type(4))) float f32x4;

struct GemmS {
    short Ahi[BM * SA];
    short Alo[BM * SA];
    short Bhi[BN * SA];
    short Blo[BN * SA];
    float bias[64];
};
struct NmsS {
    float4 bx[N_OBJ];
    float4 sbx[N_OBJ];
    float  sc[N_OBJ];
    float  sarea[N_OBJ];
    int    order[N_OBJ];
    int    act[N_OBJ];
};
union __align__(16) SMem {
    GemmS g;
    NmsS  n;
};

__device__ __forceinline__ short bf16_rne(float f) {
    unsigned u = __builtin_bit_cast(unsigned, f);
    unsigned r = (u + 0x7fffu + ((u >> 16) & 1u)) >> 16;
    return (short)r;
}
__device__ __forceinline__ float bf16_to_f(short h) {
    unsigned u = ((unsigned)(unsigned short)h) << 16;
    return __builtin_bit_cast(float, u);
}
__device__ __forceinline__ float iou_f(float4 a, float aa, float4 b, float ab) {
    float xx1 = fmaxf(a.x, b.x), yy1 = fmaxf(a.y, b.y);
    float xx2 = fminf(a.z, b.z), yy2 = fminf(a.w, b.w);
    float w = fmaxf(xx2 - xx1 + 1.0f, 0.0f);
    float h = fmaxf(yy2 - yy1 + 1.0f, 0.0f);
    float inter = w * h;
    return inter / (aa + ab - inter);
}

__global__ __launch_bounds__(256, 2)
void fused1(const float* __restrict__ logits, const float* __restrict__ vr,
            const float* __restrict__ boxes, const float* __restrict__ w,
            const float* __restrict__ b, float* __restrict__ out,
            int* __restrict__ keep_ws)
{
    __shared__ SMem sm;
    const int bid = blockIdx.x;
    const int tid = threadIdx.x;

    if (bid < NMS_BLOCKS) {
        // ---------------- per-class NMS (class c = bid+1) ----------------
        NmsS& S = sm.n;
        const int c = bid + 1;
        for (int r = tid; r < N_OBJ; r += 256) {
            const float* lrow = logits + r * N_CLS;
            float m = -INFINITY;
            for (int j = 0; j < N_CLS; j++) m = fmaxf(m, lrow[j]);
            float s = 0.f;
            for (int j = 0; j < N_CLS; j++) s += expf(lrow[j] - m);
            S.sc[r] = expf(lrow[c] - m) / s;
            S.bx[r] = *(const float4*)(boxes + ((size_t)r * N_CLS + c) * 4);
        }
        __syncthreads();
        // stable descending argsort via rank counting
        for (int i = tid; i < N_OBJ; i += 256) {
            float si = S.sc[i];
            int rk = 0;
            for (int j = 0; j < N_OBJ; j++) {
                float sj = S.sc[j];
                rk += (sj > si) || (sj == si && j < i);
            }
            S.order[rk] = i;
        }
        __syncthreads();
        for (int i = tid; i < N_OBJ; i += 256) {
            int o = S.order[i];
            float4 bb = S.bx[o];
            S.sbx[i] = bb;
            S.sarea[i] = (bb.z - bb.x + 1.f) * (bb.w - bb.y + 1.f);
            S.act[i] = 1;
        }
        __syncthreads();
        // greedy suppression; each thread owns sorted slots tid and tid+256
        const int j0 = tid, j1 = tid + 256;
        const float4 b0 = S.sbx[j0], b1 = S.sbx[j1];
        const float  a0r = S.sarea[j0], a1r = S.sarea[j1];
        int a0 = 1, a1 = 1;
        for (int i = 0; i < N_OBJ - 1; i++) {
            if (S.act[i]) {
                float4 bi = S.sbx[i];
                float  ari = S.sarea[i];
                if (j0 > i && a0 && iou_f(bi, ari, b0, a0r) > NMS_TH) { a0 = 0; S.act[j0] = 0; }
                if (j1 > i && a1 && iou_f(bi, ari, b1, a1r) > NMS_TH) { a1 = 0; S.act[j1] = 0; }
            }
            __syncthreads();
        }
        // act[] in sorted space == keep_sorted; scatter back to object index
        for (int i = tid; i < N_OBJ; i += 256)
            keep_ws[(size_t)c * N_OBJ + S.order[i]] = S.act[i];
    } else if (bid < GEMM_BLOCK0) {
        // ---------------- copy obj_dists2 ----------------
        const float4* src = (const float4*)logits;
        float4* dst = (float4*)out;
        const int n4 = (N_OBJ * N_CLS) / 4;
        for (int i = (bid - NMS_BLOCKS) * 256 + tid; i < n4; i += COPY_BLOCKS * 256)
            dst[i] = src[i];
    } else {
        // ---------------- rel_dists GEMM: hi/lo bf16 split, 3-term MFMA ----------------
        GemmS& G = sm.g;
        const int gb = bid - GEMM_BLOCK0;
        const size_t row0 = (size_t)gb * BM;
        const int wv = tid >> 6, lane = tid & 63;
        const int lcol = lane & 15, quad = lane >> 4;

        if (tid < 64) G.bias[tid] = (tid < N_RELCLS) ? b[tid] : 0.f;

        f32x4 acc[2][4];
#pragma unroll
        for (int mt = 0; mt < 2; mt++)
#pragma unroll
            for (int nt = 0; nt < 4; nt++)
                acc[mt][nt] = (f32x4){0.f, 0.f, 0.f, 0.f};

        const int ar = tid >> 4;         /* 0..15 */
        const int ac = (tid & 15) * 4;   /* 0..60 */

        for (int kt = 0; kt < REL_DIM / BK; ++kt) {
            __syncthreads();
            // stage A (vr tile 128x64 f32), loads first for latency hiding
            const float* Ab = vr + row0 * REL_DIM + (size_t)kt * BK;
            float4 va[8];
#pragma unroll
            for (int p = 0; p < 8; p++)
                va[p] = *(const float4*)(Ab + (size_t)(ar + p * 16) * REL_DIM + ac);
            // stage B (w tile 64x64 f32, rows >=51 zero)
            float4 vb[4];
            int br[4], bc[4];
#pragma unroll
            for (int p = 0; p < 4; p++) {
                int idx = tid + p * 256;
                br[p] = idx >> 4;
                bc[p] = (idx & 15) * 4;
                vb[p] = (float4){0.f, 0.f, 0.f, 0.f};
                if (br[p] < N_RELCLS)
                    vb[p] = *(const float4*)(w + (size_t)br[p] * REL_DIM + (size_t)kt * BK + bc[p]);
            }
#pragma unroll
            for (int p = 0; p < 8; p++) {
                int r = ar + p * 16;
                float4 v = va[p];
                short h0 = bf16_rne(v.x), h1 = bf16_rne(v.y), h2 = bf16_rne(v.z), h3 = bf16_rne(v.w);
                short l0 = bf16_rne(v.x - bf16_to_f(h0));
                short l1 = bf16_rne(v.y - bf16_to_f(h1));
                short l2 = bf16_rne(v.z - bf16_to_f(h2));
                short l3 = bf16_rne(v.w - bf16_to_f(h3));
                *(short4*)&G.Ahi[r * SA + ac] = make_short4(h0, h1, h2, h3);
                *(short4*)&G.Alo[r * SA + ac] = make_short4(l0, l1, l2, l3);
            }
#pragma unroll
            for (int p = 0; p < 4; p++) {
                float4 v = vb[p];
                short h0 = bf16_rne(v.x), h1 = bf16_rne(v.y), h2 = bf16_rne(v.z), h3 = bf16_rne(v.w);
                short l0 = bf16_rne(v.x - bf16_to_f(h0));
                short l1 = bf16_rne(v.y - bf16_to_f(h1));
                short l2 = bf16_rne(v.z - bf16_to_f(h2));
                short l3 = bf16_rne(v.w - bf16_to_f(h3));
                *(short4*)&G.Bhi[br[p] * SA + bc[p]] = make_short4(h0, h1, h2, h3);
                *(short4*)&G.Blo[br[p] * SA + bc[p]] = make_short4(l0, l1, l2, l3);
            }
            __syncthreads();
#pragma unroll
            for (int ks = 0; ks < 2; ks++) {
                const int kb = ks * 32 + quad * 8;
                bf16x8 ah[2], al[2], bh[4], bl[4];
#pragma unroll
                for (int mt = 0; mt < 2; mt++) {
                    int rr = wv * 32 + mt * 16 + lcol;
                    ah[mt] = *(const bf16x8*)&G.Ahi[rr * SA + kb];
                    al[mt] = *(const bf16x8*)&G.Alo[rr * SA + kb];
                }
#pragma unroll
                for (int nt = 0; nt < 4; nt++) {
                    int rr = nt * 16 + lcol;
                    bh[nt] = *(const bf16x8*)&G.Bhi[rr * SA + kb];
                    bl[nt] = *(const bf16x8*)&G.Blo[rr * SA + kb];
                }
#pragma unroll
                for (int mt = 0; mt < 2; mt++)
#pragma unroll
                    for (int nt = 0; nt < 4; nt++) {
                        acc[mt][nt] = __builtin_amdgcn_mfma_f32_16x16x32_bf16(ah[mt], bh[nt], acc[mt][nt], 0, 0, 0);
                        acc[mt][nt] = __builtin_amdgcn_mfma_f32_16x16x32_bf16(ah[mt], bl[nt], acc[mt][nt], 0, 0, 0);
                        acc[mt][nt] = __builtin_amdgcn_mfma_f32_16x16x32_bf16(al[mt], bh[nt], acc[mt][nt], 0, 0, 0);
                    }
            }
        }
        // epilogue: C/D layout col=lane&15, row=quad*4+reg (m89-verified)
        float* orel = out + OUT_REL_OFF;
#pragma unroll
        for (int mt = 0; mt < 2; mt++)
#pragma unroll
            for (int nt = 0; nt < 4; nt++) {
                int col = nt * 16 + lcol;
                if (col < N_RELCLS) {
                    float bb = G.bias[col];
#pragma unroll
                    for (int r2 = 0; r2 < 4; r2++) {
                        size_t row = row0 + wv * 32 + mt * 16 + quad * 4 + r2;
                        orel[row * N_RELCLS + col] = acc[mt][nt][r2] + bb;
                    }
                }
            }
    }
}

__global__ __launch_bounds__(256)
void pred_kernel(const float* __restrict__ logits, const int* __restrict__ keep_ws,
                 float* __restrict__ out)
{
    int r = blockIdx.x * 256 + threadIdx.x;
    if (r >= N_OBJ) return;
    const float* lrow = logits + r * N_CLS;
    float m = -INFINITY;
    for (int j = 0; j < N_CLS; j++) m = fmaxf(m, lrow[j]);
    float s = 0.f;
    for (int j = 0; j < N_CLS; j++) s += expf(lrow[j] - m);
    float bestv = -1.f;
    int bestc = 1;
    for (int c = 1; c < N_CLS; c++) {
        float p = keep_ws[(size_t)c * N_OBJ + r] ? (expf(lrow[c] - m) / s) : 0.f;
        if (p > bestv) { bestv = p; bestc = c; }  // strict > => first-max (argmax semantics)
    }
    out[OUT_PRED_OFF + r] = (float)bestc;
}

extern "C" void kernel_launch(void* const* d_in, const int* in_sizes, int n_in,
                              void* d_out, int out_size, void* d_ws, size_t ws_size,
                              hipStream_t stream)
{
    const float* logits = (const float*)d_in[0];
    const float* vr     = (const float*)d_in[1];
    const float* boxes  = (const float*)d_in[2];
    const float* w      = (const float*)d_in[3];
    const float* b      = (const float*)d_in[4];
    float* out = (float*)d_out;
    int* keep_ws = (int*)d_ws;

    const int grid = GEMM_BLOCK0 + GEMM_BLOCKS; /* 150 nms + 8 copy + 512 gemm */
    fused1<<<grid, 256, 0, stream>>>(logits, vr, boxes, w, b, out, keep_ws);
    pred_kernel<<<2, 256, 0, stream>>>(logits, keep_ws, out);
}

// Round 2
// 1604.010 us; speedup vs baseline: 1.0762x; 1.0762x over previous
//
#include <hip/hip_runtime.h>
#include <math.h>

#define NMS_TH 0.3f

#define N_OBJ 512
#define N_CLS 151
#define REL_DIM 4096
#define N_REL 65536
#define N_RELCLS 51

#define BM 64
#define BN 64
#define BK 64
#define NKT (REL_DIM / BK)  /* 64 */
#define SA 72  /* LDS leading-dim in shorts: BK + 8 pad -> frag b128 reads are 2-way (free) */

#define OUT_PRED_OFF (N_OBJ * N_CLS)          /* 77312 */
#define OUT_REL_OFF  (OUT_PRED_OFF + N_OBJ)   /* 77824 */

#define NMS_BLOCKS 150
#define COPY_BLOCKS 8
#define GEMM_BLOCK0 (NMS_BLOCKS + COPY_BLOCKS)
#define GEMM_BLOCKS (N_REL / BM)              /* 1024 */

typedef __attribute__((ext_vector_type(8))) short bf16x8;
typedef __attribute__((ext_vector_type(4))) float f32x4;

struct GemmS {
    short A[2][BM * SA];   /* 2 x 18432 B */
    short B[2][BN * SA];   /* 2 x 9216*2 B */
    float bias[64];
};
struct NmsS {
    float4 bx[N_OBJ];
    float4 sbx[N_OBJ];
    float  sc[N_OBJ];
    float  sarea[N_OBJ];
    int    order[N_OBJ];
    int    act[N_OBJ];
};
union __align__(16) SMem {
    GemmS g;   /* ~37.1 KB -> 4 blocks/CU */
    NmsS  n;   /* ~24.6 KB */
};

__device__ __forceinline__ short bf16_rne(float f) {
    unsigned u = __builtin_bit_cast(unsigned, f);
    unsigned r = (u + 0x7fffu + ((u >> 16) & 1u)) >> 16;
    return (short)r;
}
__device__ __forceinline__ float iou_f(float4 a, float aa, float4 b, float ab) {
    float xx1 = fmaxf(a.x, b.x), yy1 = fmaxf(a.y, b.y);
    float xx2 = fminf(a.z, b.z), yy2 = fminf(a.w, b.w);
    float w = fmaxf(xx2 - xx1 + 1.0f, 0.0f);
    float h = fmaxf(yy2 - yy1 + 1.0f, 0.0f);
    float inter = w * h;
    return inter / (aa + ab - inter);
}

__global__ __launch_bounds__(256, 4)
void fused1(const float* __restrict__ logits, const float* __restrict__ vr,
            const float* __restrict__ boxes, const float* __restrict__ w,
            const float* __restrict__ b, float* __restrict__ out,
            int* __restrict__ keep_ws)
{
    __shared__ SMem sm;
    const int bid = blockIdx.x;
    const int tid = threadIdx.x;

    if (bid < NMS_BLOCKS) {
        // ---------------- per-class NMS (class c = bid+1) ----------------
        NmsS& S = sm.n;
        const int c = bid + 1;
        for (int r = tid; r < N_OBJ; r += 256) {
            const float* lrow = logits + r * N_CLS;
            float m = -INFINITY;
            for (int j = 0; j < N_CLS; j++) m = fmaxf(m, lrow[j]);
            float s = 0.f;
            for (int j = 0; j < N_CLS; j++) s += expf(lrow[j] - m);
            S.sc[r] = expf(lrow[c] - m) / s;
            S.bx[r] = *(const float4*)(boxes + ((size_t)r * N_CLS + c) * 4);
        }
        __syncthreads();
        // stable descending argsort via rank counting
        for (int i = tid; i < N_OBJ; i += 256) {
            float si = S.sc[i];
            int rk = 0;
            for (int j = 0; j < N_OBJ; j++) {
                float sj = S.sc[j];
                rk += (sj > si) || (sj == si && j < i);
            }
            S.order[rk] = i;
        }
        __syncthreads();
        for (int i = tid; i < N_OBJ; i += 256) {
            int o = S.order[i];
            float4 bb = S.bx[o];
            S.sbx[i] = bb;
            S.sarea[i] = (bb.z - bb.x + 1.f) * (bb.w - bb.y + 1.f);
            S.act[i] = 1;
        }
        __syncthreads();
        // greedy suppression; each thread owns sorted slots tid and tid+256
        const int j0 = tid, j1 = tid + 256;
        const float4 b0 = S.sbx[j0], b1 = S.sbx[j1];
        const float  a0r = S.sarea[j0], a1r = S.sarea[j1];
        int a0 = 1, a1 = 1;
        for (int i = 0; i < N_OBJ - 1; i++) {
            if (S.act[i]) {
                float4 bi = S.sbx[i];
                float  ari = S.sarea[i];
                if (j0 > i && a0 && iou_f(bi, ari, b0, a0r) > NMS_TH) { a0 = 0; S.act[j0] = 0; }
                if (j1 > i && a1 && iou_f(bi, ari, b1, a1r) > NMS_TH) { a1 = 0; S.act[j1] = 0; }
            }
            __syncthreads();
        }
        for (int i = tid; i < N_OBJ; i += 256)
            keep_ws[(size_t)c * N_OBJ + S.order[i]] = S.act[i];
    } else if (bid < GEMM_BLOCK0) {
        // ---------------- copy obj_dists2 ----------------
        const float4* src = (const float4*)logits;
        float4* dst = (float4*)out;
        const int n4 = (N_OBJ * N_CLS) / 4;
        for (int i = (bid - NMS_BLOCKS) * 256 + tid; i < n4; i += COPY_BLOCKS * 256)
            dst[i] = src[i];
    } else {
        // ---------------- rel_dists GEMM: single bf16, dbuf LDS, 1 barrier/kt ----------------
        GemmS& G = sm.g;
        const int gb = bid - GEMM_BLOCK0;
        const size_t row0 = (size_t)gb * BM;
        const int wv = tid >> 6, lane = tid & 63;
        const int lcol = lane & 15, quad = lane >> 4;

        if (tid < 64) G.bias[tid] = (tid < N_RELCLS) ? b[tid] : 0.f;

        f32x4 acc[4];
#pragma unroll
        for (int nt = 0; nt < 4; nt++) acc[nt] = (f32x4){0.f, 0.f, 0.f, 0.f};

        // staging geometry: 64x64 f32 tile = 1024 float4; 4 per thread
        const int srow = tid >> 4;          /* 0..15 */
        const int scol = (tid & 15) * 4;    /* 0..60 */
        const float* Abase = vr + row0 * REL_DIM;

        float4 va[4], vb[4];

        // ---- load tile kt=0 ----
#pragma unroll
        for (int p = 0; p < 4; p++) {
            int r = srow + p * 16;
            va[p] = *(const float4*)(Abase + (size_t)r * REL_DIM + scol);
            vb[p] = (float4){0.f, 0.f, 0.f, 0.f};
            if (r < N_RELCLS)
                vb[p] = *(const float4*)(w + (size_t)r * REL_DIM + scol);
        }
        // ---- convert/store into buf 0 ----
#pragma unroll
        for (int p = 0; p < 4; p++) {
            int r = srow + p * 16;
            *(short4*)&G.A[0][r * SA + scol] =
                make_short4(bf16_rne(va[p].x), bf16_rne(va[p].y), bf16_rne(va[p].z), bf16_rne(va[p].w));
            *(short4*)&G.B[0][r * SA + scol] =
                make_short4(bf16_rne(vb[p].x), bf16_rne(vb[p].y), bf16_rne(vb[p].z), bf16_rne(vb[p].w));
        }
        __syncthreads();

        int pb = 0;
        for (int kt = 0; kt < NKT; kt++) {
            // issue next tile's global loads (overlap with MFMA below)
            if (kt + 1 < NKT) {
                const float* Ak = Abase + (size_t)(kt + 1) * BK;
                const float* Bk = w + (size_t)(kt + 1) * BK;
#pragma unroll
                for (int p = 0; p < 4; p++) {
                    int r = srow + p * 16;
                    va[p] = *(const float4*)(Ak + (size_t)r * REL_DIM + scol);
                    if (r < N_RELCLS)
                        vb[p] = *(const float4*)(Bk + (size_t)r * REL_DIM + scol);
                }
            }
            // MFMA over buf pb
            const short* Ab = G.A[pb];
            const short* Bb = G.B[pb];
#pragma unroll
            for (int ks = 0; ks < 2; ks++) {
                const int kb = ks * 32 + quad * 8;
                bf16x8 af = *(const bf16x8*)&Ab[(wv * 16 + lcol) * SA + kb];
                bf16x8 bf[4];
#pragma unroll
                for (int nt = 0; nt < 4; nt++)
                    bf[nt] = *(const bf16x8*)&Bb[(nt * 16 + lcol) * SA + kb];
#pragma unroll
                for (int nt = 0; nt < 4; nt++)
                    acc[nt] = __builtin_amdgcn_mfma_f32_16x16x32_bf16(af, bf[nt], acc[nt], 0, 0, 0);
            }
            // convert/store next tile into alternate buffer
            if (kt + 1 < NKT) {
                short* An = G.A[pb ^ 1];
                short* Bn = G.B[pb ^ 1];
#pragma unroll
                for (int p = 0; p < 4; p++) {
                    int r = srow + p * 16;
                    *(short4*)&An[r * SA + scol] =
                        make_short4(bf16_rne(va[p].x), bf16_rne(va[p].y), bf16_rne(va[p].z), bf16_rne(va[p].w));
                    *(short4*)&Bn[r * SA + scol] =
                        make_short4(bf16_rne(vb[p].x), bf16_rne(vb[p].y), bf16_rne(vb[p].z), bf16_rne(vb[p].w));
                }
                __syncthreads();
            }
            pb ^= 1;
        }

        // epilogue: C/D layout col=lane&15, row=quad*4+reg (m89-verified)
        float* orel = out + OUT_REL_OFF;
#pragma unroll
        for (int nt = 0; nt < 4; nt++) {
            int col = nt * 16 + lcol;
            if (col < N_RELCLS) {
                float bb = G.bias[col];
#pragma unroll
                for (int r2 = 0; r2 < 4; r2++) {
                    size_t row = row0 + wv * 16 + quad * 4 + r2;
                    orel[row * N_RELCLS + col] = acc[nt][r2] + bb;
                }
            }
        }
    }
}

__global__ __launch_bounds__(256)
void pred_kernel(const float* __restrict__ logits, const int* __restrict__ keep_ws,
                 float* __restrict__ out)
{
    int r = blockIdx.x * 256 + threadIdx.x;
    if (r >= N_OBJ) return;
    const float* lrow = logits + r * N_CLS;
    float m = -INFINITY;
    for (int j = 0; j < N_CLS; j++) m = fmaxf(m, lrow[j]);
    float s = 0.f;
    for (int j = 0; j < N_CLS; j++) s += expf(lrow[j] - m);
    float bestv = -1.f;
    int bestc = 1;
    for (int c = 1; c < N_CLS; c++) {
        float p = keep_ws[(size_t)c * N_OBJ + r] ? (expf(lrow[c] - m) / s) : 0.f;
        if (p > bestv) { bestv = p; bestc = c; }  // strict > => first-max (argmax semantics)
    }
    out[OUT_PRED_OFF + r] = (float)bestc;
}

extern "C" void kernel_launch(void* const* d_in, const int* in_sizes, int n_in,
                              void* d_out, int out_size, void* d_ws, size_t ws_size,
                              hipStream_t stream)
{
    const float* logits = (const float*)d_in[0];
    const float* vr     = (const float*)d_in[1];
    const float* boxes  = (const float*)d_in[2];
    const float* w      = (const float*)d_in[3];
    const float* b      = (const float*)d_in[4];
    float* out = (float*)d_out;
    int* keep_ws = (int*)d_ws;

    const int grid = GEMM_BLOCK0 + GEMM_BLOCKS; /* 150 nms + 8 copy + 1024 gemm */
    fused1<<<grid, 256, 0, stream>>>(logits, vr, boxes, w, b, out, keep_ws);
    pred_kernel<<<2, 256, 0, stream>>>(logits, keep_ws, out);
}